// Round 8
// baseline (268.929 us; speedup 1.0000x reference)
//
#include <hip/hip_runtime.h>
#include <math.h>

#define PI_F      3.141592653f
#define TWO_PI_F  6.283185306f
#define HALF_PI_F 1.5707963265f
#define IOU_THR_F 0.1f
#define NSWEEP    4
#define WGRP      4

typedef unsigned long long u64;

__device__ __forceinline__ float limit_period_f(float v) {
    return v - floorf(v / TWO_PI_F + 0.5f) * TWO_PI_F;
}

__device__ __forceinline__ u64 shfl_u64(u64 v, int src) {
    unsigned int lo = (unsigned int)(v & 0xffffffffull);
    unsigned int hi = (unsigned int)(v >> 32);
    lo = __shfl((int)lo, src);
    hi = __shfl((int)hi, src);
    return ((u64)hi << 32) | (u64)lo;
}

// ---------------- Kernel 1: adjacency, bit-serial per-thread ------------------
// Thread owns (row i, word w): 64 in-register IoUs vs LDS-staged j-boxes.
// adjC[(size_t)w * n + i] = word w of row i. Block (0,0) inits S/R.
__global__ void adj_kernel(const float* __restrict__ boxes,
                           u64* __restrict__ adjC,
                           u64* __restrict__ S, u64* __restrict__ R,
                           int n, int words) {
    __shared__ float jS[7][64];
    int w = blockIdx.x;
    int tid = threadIdx.x;              // 256 = 4 waves
    if (blockIdx.x == 0 && blockIdx.y == 0 && tid < 64) {
        S[tid] = 0ull;
        int base = tid << 6;
        int vb = n - base;
        u64 valid = (vb >= 64) ? ~0ull : ((vb <= 0) ? 0ull : ((1ull << vb) - 1ull));
        R[tid] = ~valid;                // invalid tail = resolved nonseed
    }
    if (tid < 64) {
        int j = (w << 6) + tid;
        if (j < n) {
            float b0 = boxes[j*7+0], b1 = boxes[j*7+1], b2 = boxes[j*7+2];
            float b3 = boxes[j*7+3], b4 = boxes[j*7+4], b5 = boxes[j*7+5];
            jS[0][tid] = b0 - b5*0.5f;  jS[3][tid] = b0 + b5*0.5f;
            jS[1][tid] = b1 - b4*0.5f;  jS[4][tid] = b1 + b4*0.5f;
            jS[2][tid] = b2 - b3*0.5f;  jS[5][tid] = b2 + b3*0.5f;
            jS[6][tid] = (b5*b4)*b3;
        }
    }
    __syncthreads();
    int i = blockIdx.y * 256 + tid;
    if (i >= n) return;
    float b0 = boxes[i*7+0], b1 = boxes[i*7+1], b2 = boxes[i*7+2];
    float b3 = boxes[i*7+3], b4 = boxes[i*7+4], b5 = boxes[i*7+5];
    float lix = b0 - b5*0.5f, hix = b0 + b5*0.5f;
    float liy = b1 - b4*0.5f, hiy = b1 + b4*0.5f;
    float liz = b2 - b3*0.5f, hiz = b2 + b3*0.5f;
    float vi  = (b5*b4)*b3;
    int jmax = n - (w << 6); if (jmax > 64) jmax = 64;
    u64 word = 0ull;
    for (int jj = 0; jj < jmax; ++jj) {
        float ix = fminf(hix, jS[3][jj]) - fmaxf(lix, jS[0][jj]); ix = fmaxf(ix, 0.0f);
        float iy = fminf(hiy, jS[4][jj]) - fmaxf(liy, jS[1][jj]); iy = fmaxf(iy, 0.0f);
        float iz = fminf(hiz, jS[5][jj]) - fmaxf(liz, jS[2][jj]); iz = fmaxf(iz, 0.0f);
        float inter = (ix*iy)*iz;
        float u = fmaxf(vi + jS[6][jj] - inter, 1e-8f);
        bool pred = (inter / u) > IOU_THR_F;
        word |= ((u64)(pred ? 1 : 0)) << jj;
    }
    adjC[(size_t)w * n + i] = word;
}

// ---------------- Kernel 2: greedy-MIS sweep, 4 words/block Gauss-Seidel ------
// seed(i) <=> no earlier neighbor of i is a seed. In-group words use fresh S/R
// (lane-owned registers); cross-group via global (Jacobi across launches).
__global__ void sweep_kernel(const u64* __restrict__ adjC,
                             u64* __restrict__ S, u64* __restrict__ R,
                             int n, int words) {
    int lane = threadIdx.x;        // 64
    u64 S_reg = S[lane];
    u64 R_reg = R[lane];
    int g0 = blockIdx.x * WGRP;
    for (int w = g0; w < g0 + WGRP && w < words; ++w) {
        u64 Rw = shfl_u64(R_reg, w);
        int base = w << 6;
        int vb = n - base;
        u64 valid = (vb >= 64) ? ~0ull : ((vb <= 0) ? 0ull : ((1ull << vb) - 1ull));
        u64 unknownIn = valid & ~Rw;
        if (unknownIn == 0ull) continue;    // word fully resolved (uniform)
        int i = base + lane;
        u64 Adiag = (i < n) ? adjC[(size_t)w * n + i] : 0ull;
        // scan earlier words: any-seed / any-unknown among earlier neighbors
        u64 seenAcc = 0ull, unkAcc = 0ull;
        for (int w2 = 0; w2 < w; ++w2) {
            u64 row = (i < n) ? adjC[(size_t)w2 * n + i] : 0ull;
            seenAcc |= row & shfl_u64(S_reg, w2);
            unkAcc  |= row & ~shfl_u64(R_reg, w2);
        }
        u64 E_seen  = __ballot(seenAcc != 0ull);
        u64 Unk_ext = __ballot(unkAcc  != 0ull);
        // exact in-word greedy over unresolved bits, ascending (wave-uniform)
        u64 newSeed = shfl_u64(S_reg, w);
        u64 newRes  = Rw;
        u64 pending = unknownIn;
        while (pending) {
            int b = (int)__ffsll(pending) - 1;
            pending &= pending - 1;
            u64 rowb = shfl_u64(Adiag, b);
            u64 below = b ? ((1ull << b) - 1ull) : 0ull;
            u64 earlier = rowb & below;
            u64 bit = 1ull << b;
            bool eSeen = (E_seen >> b) & 1ull;
            bool eUnk  = (Unk_ext >> b) & 1ull;
            if (eSeen || (earlier & newSeed)) {
                newRes |= bit;                          // nonseed
            } else if (eUnk || (earlier & ~newRes)) {
                // blocked: unresolved earlier neighbor exists
            } else {
                newSeed |= bit; newRes |= bit;          // seed
            }
        }
        if (lane == w) { S_reg = newSeed; R_reg = newRes; }   // fresh for group
        if (lane == 0) { S[w] = newSeed; R[w] = newRes; }
    }
}

// ---------------- Kernel 3: indices + seedList + nclust (4 threads per j) -----
// indices[j] = rank of max-index adjacent seed (last-writer-wins semantics).
__global__ void indices_kernel(const u64* __restrict__ adjC,
                               const u64* __restrict__ S,
                               int* __restrict__ indices,
                               int* __restrict__ seedList,
                               int* __restrict__ nclust, int n, int words) {
    __shared__ u64 smS[64];
    __shared__ int wsS[64];
    __shared__ int cand[64][4];
    int tid = threadIdx.x;  // 256
    if (tid < 64) {
        u64 s = (tid < words) ? S[tid] : 0ull;
        smS[tid] = s;
        int pc = (int)__popcll(s);
        int x = pc;
        for (int o = 1; o < 64; o <<= 1) {
            int y = __shfl_up(x, o);
            if (tid >= o) x += y;
        }
        wsS[tid] = x - pc;              // exclusive scan
        if (blockIdx.x == 0 && tid == 63) *nclust = x;
    }
    __syncthreads();
    int part = tid >> 6;                // 0..3 (wave id)
    int jl = tid & 63;
    int j = blockIdx.x * 64 + jl;
    int best = -1;
    if (j < n) {
        int w0 = part << 4;
        for (int w = w0; w < w0 + 16; ++w) {
            u64 m = adjC[(size_t)w * n + j] & smS[w];   // coalesced in-wave
            if (m) best = (w << 6) + 63 - (int)__clzll(m);
        }
    }
    cand[jl][part] = best;
    __syncthreads();
    if (part == 0 && j < n) {
        int c0 = cand[jl][0], c1 = cand[jl][1], c2 = cand[jl][2], c3 = cand[jl][3];
        int b3 = max(max(c0, c1), max(c2, c3));
        int idx = 0;
        if (b3 >= 0) {
            int w = b3 >> 6, b = b3 & 63;
            u64 incl = (b >= 63) ? ~0ull : ((2ull << b) - 1ull);
            idx = wsS[w] + (int)__popcll(smS[w] & incl);  // 1-based cid
        }
        indices[j] = idx;
        int wj = j >> 6, bj = j & 63;
        if ((smS[wj] >> bj) & 1ull) {
            int rank = wsS[wj] + (int)__popcll(smS[wj] & (bj ? ((1ull << bj) - 1ull) : 0ull)) + 1;
            seedList[rank - 1] = j;
        }
    }
}

// ---------------- Kernel 4: per-cluster fusion (seed-row member gather) -------
__global__ void fusion_kernel(const float* __restrict__ boxes,
                              const float* __restrict__ scores,
                              const int* __restrict__ indices,
                              const int* __restrict__ seedListG,
                              const int* __restrict__ nclust,
                              const u64* __restrict__ adjC,
                              float* __restrict__ fused,
                              float* __restrict__ sfused,
                              int* __restrict__ validArr, int n, int words) {
    int i = blockIdx.x;           // output row; cluster id = i+1
    int lane = threadIdx.x;       // 64 = 1 wave
    int cid = i + 1;
    if (cid > *nclust) {
        if (lane < 7) fused[i*7+lane] = 0.0f;
        if (lane == 0) { sfused[i] = 0.0f; validArr[i] = 0; }
        return;
    }
    __shared__ unsigned short js[256];
    __shared__ float ms[256];
    __shared__ float ds[256];
    int s = seedListG[i];
    u64 bits = (lane < words) ? adjC[(size_t)lane * n + s] : 0ull;
    // filter: keep only nodes whose final cluster is cid
    u64 keep = 0ull;
    u64 t = bits;
    while (t) {
        int b = (int)__ffsll(t) - 1;
        t &= t - 1;
        int node = (lane << 6) + b;
        if (indices[node] == cid) keep |= (1ull << b);
    }
    int cnt = __popcll(keep);
    int x = cnt;
    for (int o = 1; o < 64; o <<= 1) {
        int y = __shfl_up(x, o);
        if (lane >= o) x += y;
    }
    int excl = x - cnt;
    int m = __shfl(x, 63);
    int pos = excl;
    t = keep;
    while (t) {
        int b = (int)__ffsll(t) - 1;
        t &= t - 1;
        js[pos++] = (unsigned short)((lane << 6) + b);
    }
    __syncthreads();
    for (int k = lane; k < m; k += 64) {
        int j = js[k];
        ms[k] = scores[j];
        ds[k] = limit_period_f(boxes[j*7+6]);
    }
    __syncthreads();
    if (lane == 0) {
        if (m == 0) {
            for (int k = 0; k < 7; ++k) fused[i*7+k] = 0.0f;
            sfused[i] = 0.0f; validArr[i] = 0;
        } else {
            // s_sum and argmax (first occurrence of max; js ascending + strict >)
            float ssum = 0.0f, smax = -1e30f; int kref = 0;
            for (int k = 0; k < m; ++k) {
                float sc = ms[k];
                ssum += sc;
                if (sc > smax) { smax = sc; kref = k; }
            }
            float refdir = ds[kref];
            float denom = fmaxf(ssum, 1e-12f);
            float sgt = 0.0f;
            float cd0=0,cd1=0,cd2=0,cd3=0,cd4=0,cd5=0;
            for (int k = 0; k < m; ++k) {
                int j = js[k];
                float sc = ms[k];
                float d = fabsf(ds[k] - refdir);
                if (d > PI_F) d = TWO_PI_F - d;
                if (d > HALF_PI_F) sgt += sc;
                float wgt = sc / denom;
                cd0 += wgt * boxes[j*7+0];
                cd1 += wgt * boxes[j*7+1];
                cd2 += wgt * boxes[j*7+2];
                cd3 += wgt * boxes[j*7+3];
                cd4 += wgt * boxes[j*7+4];
                cd5 += wgt * boxes[j*7+5];
            }
            float sle = ssum - sgt;
            bool flipGt = (sgt <= sle);
            float ssin = 0.0f, scos = 0.0f;
            for (int k = 0; k < m; ++k) {
                float sc = ms[k];
                float dj = ds[k];
                float d = fabsf(dj - refdir);
                if (d > PI_F) d = TWO_PI_F - d;
                bool gt = d > HALF_PI_F;
                bool flip = flipGt ? gt : !gt;
                float adj_d = limit_period_f(dj + (flip ? PI_F : 0.0f));
                float wgt = sc / denom;
                ssin += sinf(adj_d) * wgt;
                scos += cosf(adj_d) * wgt;
            }
            float theta = atan2f(ssin, scos);
            // s_fused: sort member scores descending, sum s_k^(k+1)
            for (int k = 1; k < m; ++k) {
                float key = ms[k]; int p = k - 1;
                while (p >= 0 && ms[p] < key) { ms[p+1] = ms[p]; --p; }
                ms[p+1] = key;
            }
            float sf = 0.0f;
            for (int k = 0; k < m; ++k) sf += powf(ms[k], (float)(k+1));
            sf = fminf(sf, 1.0f);
            // corners range check
            float c_ = cosf(theta), s_ = sinf(theta);
            float wdim = cd4, ldim = cd5;
            const float xs[4]  = {0.5f, 0.5f, -0.5f, -0.5f};
            const float ys_[4] = {-0.5f, 0.5f, 0.5f, -0.5f};
            bool inr = true;
            for (int c = 0; c < 4; ++c) {
                float cx = ldim * xs[c], cy = wdim * ys_[c];
                float rx = cx*c_ - cy*s_ + cd0;
                float ry = cx*s_ + cy*c_ + cd1;
                inr = inr && (rx > -140.8f) && (rx < 140.8f) && (ry > -40.0f) && (ry < 40.0f);
            }
            fused[i*7+0]=cd0; fused[i*7+1]=cd1; fused[i*7+2]=cd2;
            fused[i*7+3]=cd3; fused[i*7+4]=cd4; fused[i*7+5]=cd5;
            fused[i*7+6]=theta;
            sfused[i] = sf;
            validArr[i] = inr ? 1 : 0;
        }
    }
}

// ---------------- Kernel 5: cumsum + gated output writes ----------------
__global__ void finalize_kernel(const float* __restrict__ fused,
                                const float* __restrict__ sfused,
                                const int* __restrict__ validArr,
                                const int* __restrict__ indices,
                                float* __restrict__ out, int n) {
    __shared__ int newidS[4096];
    __shared__ unsigned char validS[4096];
    __shared__ int scanBuf[1024];
    int tid = threadIdx.x;  // 1024
    int per = (n + 1023) >> 10;  // 4
    int base = tid * per;
    int v[8];
    int sum = 0;
    for (int k = 0; k < per && k < 8; ++k) {
        int j = base + k;
        int vv = (j < n) ? validArr[j] : 0;
        v[k] = vv; sum += vv;
    }
    scanBuf[tid] = sum;
    __syncthreads();
    for (int o = 1; o < 1024; o <<= 1) {
        int val = scanBuf[tid];
        int add = (tid >= o) ? scanBuf[tid - o] : 0;
        __syncthreads();
        scanBuf[tid] = val + add;
        __syncthreads();
    }
    int run = scanBuf[tid] - sum;
    for (int k = 0; k < per && k < 8; ++k) {
        int j = base + k;
        if (j < n) { run += v[k]; newidS[j] = run; validS[j] = (unsigned char)v[k]; }
    }
    __syncthreads();
    float* boxesO  = out;
    float* scoresO = out + (size_t)7*n;
    float* validO  = out + (size_t)8*n;
    float* idxO    = out + (size_t)9*n;
    for (int j = tid; j < n; j += 1024) {
        int vv = validS[j];
        #pragma unroll
        for (int k = 0; k < 7; ++k)
            boxesO[j*7+k] = vv ? fused[j*7+k] : 0.0f;
        scoresO[j] = vv ? sfused[j] : 0.0f;
        validO[j]  = vv ? 1.0f : 0.0f;
        int ind = indices[j];
        int safe = ind - 1; if (safe < 0) safe = 0;
        bool nv = (ind > 0) && (validS[safe] != 0);
        idxO[j] = nv ? (float)newidS[safe] : 0.0f;
    }
}

extern "C" void kernel_launch(void* const* d_in, const int* in_sizes, int n_in,
                              void* d_out, int out_size, void* d_ws, size_t ws_size,
                              hipStream_t stream) {
    const float* boxes  = (const float*)d_in[0];
    const float* scores = (const float*)d_in[1];
    int n = in_sizes[0] / 7;           // 4096
    int words = (n + 63) >> 6;         // 64

    char* ws = (char*)d_ws;
    size_t off = 0;
    u64* adjC = (u64*)(ws + off);
    off += (size_t)n * words * sizeof(u64);
    u64* S = (u64*)(ws + off); off += 64 * sizeof(u64);
    u64* R = (u64*)(ws + off); off += 64 * sizeof(u64);
    int* seedList = (int*)(ws + off); off += (size_t)n * sizeof(int);
    int* indices  = (int*)(ws + off); off += (size_t)n * sizeof(int);
    float* fused  = (float*)(ws + off); off += (size_t)n * 7 * sizeof(float);
    float* sfused = (float*)(ws + off); off += (size_t)n * sizeof(float);
    int* validArr = (int*)(ws + off); off += (size_t)n * sizeof(int);
    int* nclust   = (int*)(ws + off); off += sizeof(int);

    dim3 adjGrid(words, (n + 255) / 256);
    adj_kernel<<<adjGrid, 256, 0, stream>>>(boxes, adjC, S, R, n, words);
    for (int s2 = 0; s2 < NSWEEP; ++s2)
        sweep_kernel<<<(words + WGRP - 1) / WGRP, 64, 0, stream>>>(adjC, S, R, n, words);
    indices_kernel<<<(n + 63) / 64, 256, 0, stream>>>(adjC, S, indices, seedList,
                                                      nclust, n, words);
    fusion_kernel<<<n, 64, 0, stream>>>(boxes, scores, indices, seedList, nclust,
                                        adjC, fused, sfused, validArr, n, words);
    finalize_kernel<<<1, 1024, 0, stream>>>(fused, sfused, validArr, indices,
                                            (float*)d_out, n);
}

// Round 9
// 181.844 us; speedup vs baseline: 1.4789x; 1.4789x over previous
//
#include <hip/hip_runtime.h>
#include <math.h>

#define PI_F      3.141592653f
#define TWO_PI_F  6.283185306f
#define HALF_PI_F 1.5707963265f
#define IOU_THR_F 0.1f
#define ROUNDS    10

typedef unsigned long long u64;

__device__ __forceinline__ float limit_period_f(float v) {
    return v - floorf(v / TWO_PI_F + 0.5f) * TWO_PI_F;
}

__device__ __forceinline__ u64 shfl_u64(u64 v, int src) {
    unsigned int lo = (unsigned int)(v & 0xffffffffull);
    unsigned int hi = (unsigned int)(v >> 32);
    lo = __shfl((int)lo, src);
    hi = __shfl((int)hi, src);
    return ((u64)hi << 32) | (u64)lo;
}

// Agent-scope grid barrier. cnt/gen zeroed via hipMemsetAsync before launch.
__device__ __forceinline__ void gridbar(int* cnt, int* gen, int target, int nblk) {
    __syncthreads();
    if (threadIdx.x == 0) {
        __threadfence();
        int prev = __hip_atomic_fetch_add(cnt, 1, __ATOMIC_ACQ_REL, __HIP_MEMORY_SCOPE_AGENT);
        if (prev == nblk - 1) {
            __hip_atomic_store(cnt, 0, __ATOMIC_RELAXED, __HIP_MEMORY_SCOPE_AGENT);
            __hip_atomic_fetch_add(gen, 1, __ATOMIC_ACQ_REL, __HIP_MEMORY_SCOPE_AGENT);
        } else {
            while (__hip_atomic_load(gen, __ATOMIC_ACQUIRE, __HIP_MEMORY_SCOPE_AGENT) < target)
                __builtin_amdgcn_s_sleep(2);
        }
        __threadfence();
    }
    __syncthreads();
}

// ---------------- Kernel 1: adjacency, bit-serial per-thread ------------------
// Thread owns (row i, word w): 64 in-register IoUs vs LDS-staged j-boxes.
// adjC[(size_t)w * n + i] = word w of row i.
__global__ void adj_kernel(const float* __restrict__ boxes,
                           u64* __restrict__ adjC, int n, int words) {
    __shared__ float jS[7][64];
    int w = blockIdx.x;
    int tid = threadIdx.x;              // 256 = 4 waves
    if (tid < 64) {
        int j = (w << 6) + tid;
        if (j < n) {
            float b0 = boxes[j*7+0], b1 = boxes[j*7+1], b2 = boxes[j*7+2];
            float b3 = boxes[j*7+3], b4 = boxes[j*7+4], b5 = boxes[j*7+5];
            jS[0][tid] = b0 - b5*0.5f;  jS[3][tid] = b0 + b5*0.5f;
            jS[1][tid] = b1 - b4*0.5f;  jS[4][tid] = b1 + b4*0.5f;
            jS[2][tid] = b2 - b3*0.5f;  jS[5][tid] = b2 + b3*0.5f;
            jS[6][tid] = (b5*b4)*b3;
        }
    }
    __syncthreads();
    int i = blockIdx.y * 256 + tid;
    if (i >= n) return;
    float b0 = boxes[i*7+0], b1 = boxes[i*7+1], b2 = boxes[i*7+2];
    float b3 = boxes[i*7+3], b4 = boxes[i*7+4], b5 = boxes[i*7+5];
    float lix = b0 - b5*0.5f, hix = b0 + b5*0.5f;
    float liy = b1 - b4*0.5f, hiy = b1 + b4*0.5f;
    float liz = b2 - b3*0.5f, hiz = b2 + b3*0.5f;
    float vi  = (b5*b4)*b3;
    int jmax = n - (w << 6); if (jmax > 64) jmax = 64;
    u64 word = 0ull;
    for (int jj = 0; jj < jmax; ++jj) {
        float ix = fminf(hix, jS[3][jj]) - fmaxf(lix, jS[0][jj]); ix = fmaxf(ix, 0.0f);
        float iy = fminf(hiy, jS[4][jj]) - fmaxf(liy, jS[1][jj]); iy = fmaxf(iy, 0.0f);
        float iz = fminf(hiz, jS[5][jj]) - fmaxf(liz, jS[2][jj]); iz = fmaxf(iz, 0.0f);
        float inter = (ix*iy)*iz;
        float u = fmaxf(vi + jS[6][jj] - inter, 1e-8f);
        bool pred = (inter / u) > IOU_THR_F;
        word |= ((u64)(pred ? 1 : 0)) << jj;
    }
    adjC[(size_t)w * n + i] = word;
}

// ---------------- Kernel 2: persistent MIS (rounds + indices), 1 launch -------
// seed(i) <=> no earlier neighbor of i is a seed. Jacobi rounds across words,
// exact Gauss-Seidel greedy within a word; grid barrier between rounds.
// After the last barrier: indices[j] = rank of max-index adjacent seed.
__global__ __launch_bounds__(256) void mis_kernel(const u64* __restrict__ adjC,
                                                  u64* __restrict__ S, u64* __restrict__ R,
                                                  int* __restrict__ indices,
                                                  int* __restrict__ seedList,
                                                  int* __restrict__ nclust,
                                                  int* __restrict__ bcnt, int* __restrict__ bgen,
                                                  int n, int words) {
    int w = blockIdx.x;
    int tid = threadIdx.x;         // 256
    int lane = tid & 63, wv = tid >> 6;
    __shared__ u64 accS[4][64];
    __shared__ u64 accU[4][64];
    int base = w << 6;
    int vb = n - base;
    u64 valid = (vb >= 64) ? ~0ull : ((vb <= 0) ? 0ull : ((1ull << vb) - 1ull));
    if (tid == 0) {
        __hip_atomic_store(&S[w], 0ull,  __ATOMIC_RELAXED, __HIP_MEMORY_SCOPE_AGENT);
        __hip_atomic_store(&R[w], ~valid, __ATOMIC_RELAXED, __HIP_MEMORY_SCOPE_AGENT);
    }
    gridbar(bcnt, bgen, 1, gridDim.x);
    for (int r = 0; r < ROUNDS; ++r) {
        u64 S_l = __hip_atomic_load(&S[lane], __ATOMIC_RELAXED, __HIP_MEMORY_SCOPE_AGENT);
        u64 R_l = __hip_atomic_load(&R[lane], __ATOMIC_RELAXED, __HIP_MEMORY_SCOPE_AGENT);
        u64 Rw = shfl_u64(R_l, w);
        u64 unknownIn = valid & ~Rw;             // block-uniform
        if (unknownIn != 0ull) {
            int i = base + lane;
            u64 sA = 0ull, uA = 0ull;
            for (int w2 = wv; w2 < w; w2 += 4) {  // wave-split scan
                u64 row = (i < n) ? adjC[(size_t)w2 * n + i] : 0ull;
                sA |= row & shfl_u64(S_l, w2);
                uA |= row & ~shfl_u64(R_l, w2);
            }
            accS[wv][lane] = sA; accU[wv][lane] = uA;
            u64 Adiag = (wv == 0 && i < n) ? adjC[(size_t)w * n + i] : 0ull;
            __syncthreads();
            if (wv == 0) {
                u64 seenAcc = accS[0][lane] | accS[1][lane] | accS[2][lane] | accS[3][lane];
                u64 unkAcc  = accU[0][lane] | accU[1][lane] | accU[2][lane] | accU[3][lane];
                u64 E_seen  = __ballot(seenAcc != 0ull);
                u64 Unk_ext = __ballot(unkAcc  != 0ull);
                // exact in-word greedy over unresolved bits, ascending
                u64 newSeed = shfl_u64(S_l, w);
                u64 newRes  = Rw;
                u64 pending = unknownIn;
                while (pending) {
                    int b = (int)__ffsll(pending) - 1;
                    pending &= pending - 1;
                    u64 rowb = shfl_u64(Adiag, b);
                    u64 below = b ? ((1ull << b) - 1ull) : 0ull;
                    u64 earlier = rowb & below;
                    u64 bit = 1ull << b;
                    bool eSeen = (E_seen >> b) & 1ull;
                    bool eUnk  = (Unk_ext >> b) & 1ull;
                    if (eSeen || (earlier & newSeed)) {
                        newRes |= bit;                      // nonseed
                    } else if (eUnk || (earlier & ~newRes)) {
                        // blocked: unresolved earlier neighbor
                    } else {
                        newSeed |= bit; newRes |= bit;      // seed
                    }
                }
                if (lane == 0) {
                    __hip_atomic_store(&S[w], newSeed, __ATOMIC_RELAXED, __HIP_MEMORY_SCOPE_AGENT);
                    __hip_atomic_store(&R[w], newRes,  __ATOMIC_RELAXED, __HIP_MEMORY_SCOPE_AGENT);
                }
            }
        }
        gridbar(bcnt, bgen, r + 2, gridDim.x);
    }
    // ---- indices phase (S final) ----
    __shared__ u64 smS[64];
    __shared__ int wsS[64];
    __shared__ int cand[64][4];
    __shared__ int totS;
    if (tid < 64) {
        u64 s = (tid < words) ? __hip_atomic_load(&S[tid], __ATOMIC_RELAXED, __HIP_MEMORY_SCOPE_AGENT) : 0ull;
        smS[tid] = s;
        int pc = (int)__popcll(s);
        int x = pc;
        for (int o = 1; o < 64; o <<= 1) {
            int y = __shfl_up(x, o);
            if (tid >= o) x += y;
        }
        wsS[tid] = x - pc;              // exclusive scan
        if (tid == 63) totS = x;
    }
    __syncthreads();
    if (w == 0 && tid == 0) *nclust = totS;
    int j = base + lane;
    int best = -1;
    if (j < n) {
        int w0 = wv << 4;
        int wend = w0 + 16; if (wend > words) wend = words;
        for (int w2 = w0; w2 < wend; ++w2) {
            u64 m = adjC[(size_t)w2 * n + j] & smS[w2];   // coalesced
            if (m) best = (w2 << 6) + 63 - (int)__clzll(m);
        }
    }
    cand[lane][wv] = best;
    __syncthreads();
    if (wv == 0 && j < n) {
        int b3 = max(max(cand[lane][0], cand[lane][1]), max(cand[lane][2], cand[lane][3]));
        int idx = 0;
        if (b3 >= 0) {
            int w2 = b3 >> 6, b = b3 & 63;
            u64 incl = (b >= 63) ? ~0ull : ((2ull << b) - 1ull);
            idx = wsS[w2] + (int)__popcll(smS[w2] & incl);  // 1-based cid
        }
        indices[j] = idx;
        int wj = j >> 6, bj = j & 63;
        if ((smS[wj] >> bj) & 1ull) {
            int rank = wsS[wj] + (int)__popcll(smS[wj] & (bj ? ((1ull << bj) - 1ull) : 0ull)) + 1;
            seedList[rank - 1] = j;
        }
    }
}

// ---------------- Kernel 3: per-cluster fusion (grid-stride, 1 wave/block) ----
__global__ void fusion_kernel(const float* __restrict__ boxes,
                              const float* __restrict__ scores,
                              const int* __restrict__ indices,
                              const int* __restrict__ seedListG,
                              const int* __restrict__ nclust,
                              const u64* __restrict__ adjC,
                              float* __restrict__ fused,
                              float* __restrict__ sfused,
                              int* __restrict__ validArr, int n, int words) {
    int lane = threadIdx.x;       // 64 = 1 wave
    int nc = *nclust;
    __shared__ unsigned short js[256];
    __shared__ float ms[256];
    __shared__ float ds[256];
    for (int i = blockIdx.x; i < n; i += gridDim.x) {
        int cid = i + 1;
        if (cid > nc) {
            if (lane < 7) fused[i*7+lane] = 0.0f;
            if (lane == 0) { sfused[i] = 0.0f; validArr[i] = 0; }
            continue;
        }
        int s = seedListG[i];
        u64 bits = (lane < words) ? adjC[(size_t)lane * n + s] : 0ull;
        // filter: keep only nodes whose final cluster is cid
        u64 keep = 0ull;
        u64 t = bits;
        while (t) {
            int b = (int)__ffsll(t) - 1;
            t &= t - 1;
            int node = (lane << 6) + b;
            if (indices[node] == cid) keep |= (1ull << b);
        }
        int cnt = __popcll(keep);
        int x = cnt;
        for (int o = 1; o < 64; o <<= 1) {
            int y = __shfl_up(x, o);
            if (lane >= o) x += y;
        }
        int excl = x - cnt;
        int m = __shfl(x, 63);
        int pos = excl;
        t = keep;
        while (t) {
            int b = (int)__ffsll(t) - 1;
            t &= t - 1;
            js[pos++] = (unsigned short)((lane << 6) + b);
        }
        __syncthreads();
        for (int k = lane; k < m; k += 64) {
            int j = js[k];
            ms[k] = scores[j];
            ds[k] = limit_period_f(boxes[j*7+6]);
        }
        __syncthreads();
        if (lane == 0) {
            if (m == 0) {
                for (int k = 0; k < 7; ++k) fused[i*7+k] = 0.0f;
                sfused[i] = 0.0f; validArr[i] = 0;
            } else {
                // s_sum and argmax (first occurrence of max; js ascending + strict >)
                float ssum = 0.0f, smax = -1e30f; int kref = 0;
                for (int k = 0; k < m; ++k) {
                    float sc = ms[k];
                    ssum += sc;
                    if (sc > smax) { smax = sc; kref = k; }
                }
                float refdir = ds[kref];
                float denom = fmaxf(ssum, 1e-12f);
                float sgt = 0.0f;
                float cd0=0,cd1=0,cd2=0,cd3=0,cd4=0,cd5=0;
                for (int k = 0; k < m; ++k) {
                    int j = js[k];
                    float sc = ms[k];
                    float d = fabsf(ds[k] - refdir);
                    if (d > PI_F) d = TWO_PI_F - d;
                    if (d > HALF_PI_F) sgt += sc;
                    float wgt = sc / denom;
                    cd0 += wgt * boxes[j*7+0];
                    cd1 += wgt * boxes[j*7+1];
                    cd2 += wgt * boxes[j*7+2];
                    cd3 += wgt * boxes[j*7+3];
                    cd4 += wgt * boxes[j*7+4];
                    cd5 += wgt * boxes[j*7+5];
                }
                float sle = ssum - sgt;
                bool flipGt = (sgt <= sle);
                float ssin = 0.0f, scos = 0.0f;
                for (int k = 0; k < m; ++k) {
                    float sc = ms[k];
                    float dj = ds[k];
                    float d = fabsf(dj - refdir);
                    if (d > PI_F) d = TWO_PI_F - d;
                    bool gt = d > HALF_PI_F;
                    bool flip = flipGt ? gt : !gt;
                    float adj_d = limit_period_f(dj + (flip ? PI_F : 0.0f));
                    float wgt = sc / denom;
                    ssin += sinf(adj_d) * wgt;
                    scos += cosf(adj_d) * wgt;
                }
                float theta = atan2f(ssin, scos);
                // s_fused: sort member scores descending, sum s_k^(k+1)
                for (int k = 1; k < m; ++k) {
                    float key = ms[k]; int p = k - 1;
                    while (p >= 0 && ms[p] < key) { ms[p+1] = ms[p]; --p; }
                    ms[p+1] = key;
                }
                float sf = 0.0f;
                for (int k = 0; k < m; ++k) sf += powf(ms[k], (float)(k+1));
                sf = fminf(sf, 1.0f);
                // corners range check
                float c_ = cosf(theta), s_ = sinf(theta);
                float wdim = cd4, ldim = cd5;
                const float xs[4]  = {0.5f, 0.5f, -0.5f, -0.5f};
                const float ys_[4] = {-0.5f, 0.5f, 0.5f, -0.5f};
                bool inr = true;
                for (int c = 0; c < 4; ++c) {
                    float cx = ldim * xs[c], cy = wdim * ys_[c];
                    float rx = cx*c_ - cy*s_ + cd0;
                    float ry = cx*s_ + cy*c_ + cd1;
                    inr = inr && (rx > -140.8f) && (rx < 140.8f) && (ry > -40.0f) && (ry < 40.0f);
                }
                fused[i*7+0]=cd0; fused[i*7+1]=cd1; fused[i*7+2]=cd2;
                fused[i*7+3]=cd3; fused[i*7+4]=cd4; fused[i*7+5]=cd5;
                fused[i*7+6]=theta;
                sfused[i] = sf;
                validArr[i] = inr ? 1 : 0;
            }
        }
        __syncthreads();
    }
}

// ---------------- Kernel 4: cumsum + gated output writes ----------------
__global__ void finalize_kernel(const float* __restrict__ fused,
                                const float* __restrict__ sfused,
                                const int* __restrict__ validArr,
                                const int* __restrict__ indices,
                                float* __restrict__ out, int n) {
    __shared__ int newidS[4096];
    __shared__ unsigned char validS[4096];
    __shared__ int scanBuf[1024];
    int tid = threadIdx.x;  // 1024
    int per = (n + 1023) >> 10;  // 4
    int base = tid * per;
    int v[8];
    int sum = 0;
    for (int k = 0; k < per && k < 8; ++k) {
        int j = base + k;
        int vv = (j < n) ? validArr[j] : 0;
        v[k] = vv; sum += vv;
    }
    scanBuf[tid] = sum;
    __syncthreads();
    for (int o = 1; o < 1024; o <<= 1) {
        int val = scanBuf[tid];
        int add = (tid >= o) ? scanBuf[tid - o] : 0;
        __syncthreads();
        scanBuf[tid] = val + add;
        __syncthreads();
    }
    int run = scanBuf[tid] - sum;
    for (int k = 0; k < per && k < 8; ++k) {
        int j = base + k;
        if (j < n) { run += v[k]; newidS[j] = run; validS[j] = (unsigned char)v[k]; }
    }
    __syncthreads();
    float* boxesO  = out;
    float* scoresO = out + (size_t)7*n;
    float* validO  = out + (size_t)8*n;
    float* idxO    = out + (size_t)9*n;
    for (int j = tid; j < n; j += 1024) {
        int vv = validS[j];
        #pragma unroll
        for (int k = 0; k < 7; ++k)
            boxesO[j*7+k] = vv ? fused[j*7+k] : 0.0f;
        scoresO[j] = vv ? sfused[j] : 0.0f;
        validO[j]  = vv ? 1.0f : 0.0f;
        int ind = indices[j];
        int safe = ind - 1; if (safe < 0) safe = 0;
        bool nv = (ind > 0) && (validS[safe] != 0);
        idxO[j] = nv ? (float)newidS[safe] : 0.0f;
    }
}

extern "C" void kernel_launch(void* const* d_in, const int* in_sizes, int n_in,
                              void* d_out, int out_size, void* d_ws, size_t ws_size,
                              hipStream_t stream) {
    const float* boxes  = (const float*)d_in[0];
    const float* scores = (const float*)d_in[1];
    int n = in_sizes[0] / 7;           // 4096
    int words = (n + 63) >> 6;         // 64

    char* ws = (char*)d_ws;
    size_t off = 0;
    u64* adjC = (u64*)(ws + off);
    off += (size_t)n * words * sizeof(u64);
    u64* S = (u64*)(ws + off); off += 64 * sizeof(u64);
    u64* R = (u64*)(ws + off); off += 64 * sizeof(u64);
    int* seedList = (int*)(ws + off); off += (size_t)n * sizeof(int);
    int* indices  = (int*)(ws + off); off += (size_t)n * sizeof(int);
    float* fused  = (float*)(ws + off); off += (size_t)n * 7 * sizeof(float);
    float* sfused = (float*)(ws + off); off += (size_t)n * sizeof(float);
    int* validArr = (int*)(ws + off); off += (size_t)n * sizeof(int);
    int* nclust   = (int*)(ws + off); off += sizeof(int);
    off = (off + 7) & ~(size_t)7;
    int* barrier  = (int*)(ws + off); off += 2 * sizeof(int);   // {cnt, gen}

    hipMemsetAsync(barrier, 0, 2 * sizeof(int), stream);
    dim3 adjGrid(words, (n + 255) / 256);
    adj_kernel<<<adjGrid, 256, 0, stream>>>(boxes, adjC, n, words);
    mis_kernel<<<words, 256, 0, stream>>>(adjC, S, R, indices, seedList, nclust,
                                          barrier, barrier + 1, n, words);
    fusion_kernel<<<512, 64, 0, stream>>>(boxes, scores, indices, seedList, nclust,
                                          adjC, fused, sfused, validArr, n, words);
    finalize_kernel<<<1, 1024, 0, stream>>>(fused, sfused, validArr, indices,
                                            (float*)d_out, n);
}

// Round 10
// 147.748 us; speedup vs baseline: 1.8202x; 1.2308x over previous
//
#include <hip/hip_runtime.h>
#include <math.h>

#define PI_F      3.141592653f
#define TWO_PI_F  6.283185306f
#define HALF_PI_F 1.5707963265f
#define IOU_THR_F 0.1f
#define ROUNDS_MAX 16

typedef unsigned long long u64;

__device__ __forceinline__ float limit_period_f(float v) {
    return v - floorf(v / TWO_PI_F + 0.5f) * TWO_PI_F;
}

__device__ __forceinline__ u64 shfl_u64(u64 v, int src) {
    unsigned int lo = (unsigned int)(v & 0xffffffffull);
    unsigned int hi = (unsigned int)(v >> 32);
    lo = __shfl((int)lo, src);
    hi = __shfl((int)hi, src);
    return ((u64)hi << 32) | (u64)lo;
}

// Agent-scope grid barrier. cnt/gen zeroed via hipMemsetAsync before launch.
__device__ __forceinline__ void gridbar(int* cnt, int* gen, int target, int nblk) {
    __syncthreads();
    if (threadIdx.x == 0) {
        __threadfence();
        int prev = __hip_atomic_fetch_add(cnt, 1, __ATOMIC_ACQ_REL, __HIP_MEMORY_SCOPE_AGENT);
        if (prev == nblk - 1) {
            __hip_atomic_store(cnt, 0, __ATOMIC_RELAXED, __HIP_MEMORY_SCOPE_AGENT);
            __hip_atomic_fetch_add(gen, 1, __ATOMIC_ACQ_REL, __HIP_MEMORY_SCOPE_AGENT);
        } else {
            while (__hip_atomic_load(gen, __ATOMIC_ACQUIRE, __HIP_MEMORY_SCOPE_AGENT) < target)
                __builtin_amdgcn_s_sleep(2);
        }
        __threadfence();
    }
    __syncthreads();
}

// ---------------- Kernel 1: adjacency + word-occupancy mask -------------------
// Thread owns (row i, word w): 64 in-register IoUs vs LDS-staged j-boxes.
// adjC[(size_t)w * n + i] = word w of row i.
// occMask[rb] bit w = any row in block [64rb,64rb+64) has nonzero word w.
__global__ void adj_kernel(const float* __restrict__ boxes,
                           u64* __restrict__ adjC, u64* __restrict__ occMask,
                           int n, int words) {
    __shared__ float jS[7][64];
    int w = blockIdx.x;
    int tid = threadIdx.x;              // 256 = 4 waves
    int lane = tid & 63, wv = tid >> 6;
    if (tid < 64) {
        int j = (w << 6) + tid;
        if (j < n) {
            float b0 = boxes[j*7+0], b1 = boxes[j*7+1], b2 = boxes[j*7+2];
            float b3 = boxes[j*7+3], b4 = boxes[j*7+4], b5 = boxes[j*7+5];
            jS[0][tid] = b0 - b5*0.5f;  jS[3][tid] = b0 + b5*0.5f;
            jS[1][tid] = b1 - b4*0.5f;  jS[4][tid] = b1 + b4*0.5f;
            jS[2][tid] = b2 - b3*0.5f;  jS[5][tid] = b2 + b3*0.5f;
            jS[6][tid] = (b5*b4)*b3;
        }
    }
    __syncthreads();
    int i = blockIdx.y * 256 + tid;
    if (i >= n) return;
    float b0 = boxes[i*7+0], b1 = boxes[i*7+1], b2 = boxes[i*7+2];
    float b3 = boxes[i*7+3], b4 = boxes[i*7+4], b5 = boxes[i*7+5];
    float lix = b0 - b5*0.5f, hix = b0 + b5*0.5f;
    float liy = b1 - b4*0.5f, hiy = b1 + b4*0.5f;
    float liz = b2 - b3*0.5f, hiz = b2 + b3*0.5f;
    float vi  = (b5*b4)*b3;
    int jmax = n - (w << 6); if (jmax > 64) jmax = 64;
    u64 word = 0ull;
    for (int jj = 0; jj < jmax; ++jj) {
        float ix = fminf(hix, jS[3][jj]) - fmaxf(lix, jS[0][jj]); ix = fmaxf(ix, 0.0f);
        float iy = fminf(hiy, jS[4][jj]) - fmaxf(liy, jS[1][jj]); iy = fmaxf(iy, 0.0f);
        float iz = fminf(hiz, jS[5][jj]) - fmaxf(liz, jS[2][jj]); iz = fmaxf(iz, 0.0f);
        float inter = (ix*iy)*iz;
        float u = fmaxf(vi + jS[6][jj] - inter, 1e-8f);
        bool pred = (inter / u) > IOU_THR_F;
        word |= ((u64)(pred ? 1 : 0)) << jj;
    }
    adjC[(size_t)w * n + i] = word;
    u64 bal = __ballot(word != 0ull);
    if (lane == 0 && bal)
        atomicOr(&occMask[blockIdx.y * 4 + wv], 1ull << w);
}

// ---------------- Kernel 2: persistent MIS (rounds + indices), 1 launch -------
// seed(i) <=> no earlier neighbor of i is a seed. Jacobi rounds across words,
// exact greedy within a word; occ-mask skips empty columns; early-exit on
// global convergence. After: indices[j] = rank of max-index adjacent seed.
__global__ __launch_bounds__(256) void mis_kernel(const u64* __restrict__ adjC,
                                                  const u64* __restrict__ occMask,
                                                  u64* __restrict__ S, u64* __restrict__ R,
                                                  int* __restrict__ indices,
                                                  int* __restrict__ seedList,
                                                  int* __restrict__ nclust,
                                                  int* __restrict__ unresolvedCnt,
                                                  int* __restrict__ bcnt, int* __restrict__ bgen,
                                                  int n, int words) {
    int w = blockIdx.x;
    int tid = threadIdx.x;         // 256
    int lane = tid & 63, wv = tid >> 6;
    __shared__ u64 accS[4][64];
    __shared__ u64 accU[4][64];
    int base = w << 6;
    int vb = n - base;
    u64 valid = (vb >= 64) ? ~0ull : ((vb <= 0) ? 0ull : ((1ull << vb) - 1ull));
    if (tid == 0) {
        __hip_atomic_store(&S[w], 0ull,  __ATOMIC_RELAXED, __HIP_MEMORY_SCOPE_AGENT);
        __hip_atomic_store(&R[w], ~valid, __ATOMIC_RELAXED, __HIP_MEMORY_SCOPE_AGENT);
    }
    u64 occ = occMask[w];
    u64 occEarlier = occ & (w ? ((1ull << w) - 1ull) : 0ull);
    gridbar(bcnt, bgen, 1, gridDim.x);
    for (int r = 0; r < ROUNDS_MAX; ++r) {
        u64 S_l = __hip_atomic_load(&S[lane], __ATOMIC_RELAXED, __HIP_MEMORY_SCOPE_AGENT);
        u64 R_l = __hip_atomic_load(&R[lane], __ATOMIC_RELAXED, __HIP_MEMORY_SCOPE_AGENT);
        u64 Rw = shfl_u64(R_l, w);
        u64 unknownIn = valid & ~Rw;             // block-uniform
        if (unknownIn != 0ull) {
            int i = base + lane;
            u64 sA = 0ull, uA = 0ull;
            u64 tmp = occEarlier;                 // only nonzero earlier words
            int bi = 0;
            while (tmp) {
                int w2 = (int)__ffsll(tmp) - 1; tmp &= tmp - 1;
                if ((bi & 3) == wv) {
                    u64 row = (i < n) ? adjC[(size_t)w2 * n + i] : 0ull;
                    sA |= row & shfl_u64(S_l, w2);
                    uA |= row & ~shfl_u64(R_l, w2);
                }
                ++bi;
            }
            accS[wv][lane] = sA; accU[wv][lane] = uA;
            u64 Adiag = (wv == 0 && base + lane < n) ? adjC[(size_t)w * n + (base + lane)] : 0ull;
            __syncthreads();
            if (wv == 0) {
                u64 seenAcc = accS[0][lane] | accS[1][lane] | accS[2][lane] | accS[3][lane];
                u64 unkAcc  = accU[0][lane] | accU[1][lane] | accU[2][lane] | accU[3][lane];
                u64 E_seen  = __ballot(seenAcc != 0ull);
                u64 Unk_ext = __ballot(unkAcc  != 0ull);
                // exact in-word greedy over unresolved bits, ascending
                u64 newSeed = shfl_u64(S_l, w);
                u64 newRes  = Rw;
                u64 pending = unknownIn;
                while (pending) {
                    int b = (int)__ffsll(pending) - 1;
                    pending &= pending - 1;
                    u64 rowb = shfl_u64(Adiag, b);
                    u64 below = b ? ((1ull << b) - 1ull) : 0ull;
                    u64 earlier = rowb & below;
                    u64 bit = 1ull << b;
                    bool eSeen = (E_seen >> b) & 1ull;
                    bool eUnk  = (Unk_ext >> b) & 1ull;
                    if (eSeen || (earlier & newSeed)) {
                        newRes |= bit;                      // nonseed
                    } else if (eUnk || (earlier & ~newRes)) {
                        // blocked: unresolved earlier neighbor
                    } else {
                        newSeed |= bit; newRes |= bit;      // seed
                    }
                }
                if (lane == 0) {
                    __hip_atomic_store(&S[w], newSeed, __ATOMIC_RELAXED, __HIP_MEMORY_SCOPE_AGENT);
                    __hip_atomic_store(&R[w], newRes,  __ATOMIC_RELAXED, __HIP_MEMORY_SCOPE_AGENT);
                    if (newRes != valid)
                        __hip_atomic_fetch_add(&unresolvedCnt[r], 1, __ATOMIC_ACQ_REL, __HIP_MEMORY_SCOPE_AGENT);
                }
            }
        }
        gridbar(bcnt, bgen, r + 2, gridDim.x);
        int unc = __hip_atomic_load(&unresolvedCnt[r], __ATOMIC_ACQUIRE, __HIP_MEMORY_SCOPE_AGENT);
        if (unc == 0) break;                     // uniform across all blocks
    }
    // ---- indices phase (S final) ----
    __shared__ u64 smS[64];
    __shared__ int wsS[64];
    __shared__ int totS;
    if (tid < 64) {
        u64 s = (tid < words) ? __hip_atomic_load(&S[tid], __ATOMIC_RELAXED, __HIP_MEMORY_SCOPE_AGENT) : 0ull;
        smS[tid] = s;
        int pc = (int)__popcll(s);
        int x = pc;
        for (int o = 1; o < 64; o <<= 1) {
            int y = __shfl_up(x, o);
            if (tid >= o) x += y;
        }
        wsS[tid] = x - pc;              // exclusive scan
        if (tid == 63) totS = x;
    }
    __syncthreads();
    if (w == 0 && tid == 0) *nclust = totS;
    if (wv == 0) {                      // wave 0: j = base+lane, few occ words
        int j = base + lane;
        int best = -1;
        if (j < n) {
            u64 tmp = occ;
            while (tmp) {
                int w2 = (int)__ffsll(tmp) - 1; tmp &= tmp - 1;
                u64 m = adjC[(size_t)w2 * n + j] & smS[w2];   // coalesced
                if (m) best = (w2 << 6) + 63 - (int)__clzll(m);
            }
            int idx = 0;
            if (best >= 0) {
                int w2 = best >> 6, b = best & 63;
                u64 incl = (b >= 63) ? ~0ull : ((2ull << b) - 1ull);
                idx = wsS[w2] + (int)__popcll(smS[w2] & incl);  // 1-based cid
            }
            indices[j] = idx;
            int bj = j & 63;
            if ((smS[w] >> bj) & 1ull) {
                int rank = wsS[w] + (int)__popcll(smS[w] & (bj ? ((1ull << bj) - 1ull) : 0ull)) + 1;
                seedList[rank - 1] = j;
            }
        }
    }
}

// ---------------- Kernel 3: per-cluster fusion (grid-stride, 1 wave/block) ----
__global__ void fusion_kernel(const float* __restrict__ boxes,
                              const float* __restrict__ scores,
                              const int* __restrict__ indices,
                              const int* __restrict__ seedListG,
                              const int* __restrict__ nclust,
                              const u64* __restrict__ adjC,
                              float* __restrict__ fused,
                              float* __restrict__ sfused,
                              int* __restrict__ validArr, int n, int words) {
    int lane = threadIdx.x;       // 64 = 1 wave
    int nc = *nclust;
    __shared__ unsigned short js[256];
    __shared__ float ms[256];
    __shared__ float ds[256];
    for (int i = blockIdx.x; i < n; i += gridDim.x) {
        int cid = i + 1;
        if (cid > nc) {
            if (lane < 7) fused[i*7+lane] = 0.0f;
            if (lane == 0) { sfused[i] = 0.0f; validArr[i] = 0; }
            continue;
        }
        int s = seedListG[i];
        u64 bits = (lane < words) ? adjC[(size_t)lane * n + s] : 0ull;
        // filter: keep only nodes whose final cluster is cid
        u64 keep = 0ull;
        u64 t = bits;
        while (t) {
            int b = (int)__ffsll(t) - 1;
            t &= t - 1;
            int node = (lane << 6) + b;
            if (indices[node] == cid) keep |= (1ull << b);
        }
        int cnt = __popcll(keep);
        int x = cnt;
        for (int o = 1; o < 64; o <<= 1) {
            int y = __shfl_up(x, o);
            if (lane >= o) x += y;
        }
        int excl = x - cnt;
        int m = __shfl(x, 63);
        int pos = excl;
        t = keep;
        while (t) {
            int b = (int)__ffsll(t) - 1;
            t &= t - 1;
            js[pos++] = (unsigned short)((lane << 6) + b);
        }
        __syncthreads();
        for (int k = lane; k < m; k += 64) {
            int j = js[k];
            ms[k] = scores[j];
            ds[k] = limit_period_f(boxes[j*7+6]);
        }
        __syncthreads();
        if (lane == 0) {
            if (m == 0) {
                for (int k = 0; k < 7; ++k) fused[i*7+k] = 0.0f;
                sfused[i] = 0.0f; validArr[i] = 0;
            } else {
                // s_sum and argmax (first occurrence of max; js ascending + strict >)
                float ssum = 0.0f, smax = -1e30f; int kref = 0;
                for (int k = 0; k < m; ++k) {
                    float sc = ms[k];
                    ssum += sc;
                    if (sc > smax) { smax = sc; kref = k; }
                }
                float refdir = ds[kref];
                float denom = fmaxf(ssum, 1e-12f);
                float sgt = 0.0f;
                float cd0=0,cd1=0,cd2=0,cd3=0,cd4=0,cd5=0;
                for (int k = 0; k < m; ++k) {
                    int j = js[k];
                    float sc = ms[k];
                    float d = fabsf(ds[k] - refdir);
                    if (d > PI_F) d = TWO_PI_F - d;
                    if (d > HALF_PI_F) sgt += sc;
                    float wgt = sc / denom;
                    cd0 += wgt * boxes[j*7+0];
                    cd1 += wgt * boxes[j*7+1];
                    cd2 += wgt * boxes[j*7+2];
                    cd3 += wgt * boxes[j*7+3];
                    cd4 += wgt * boxes[j*7+4];
                    cd5 += wgt * boxes[j*7+5];
                }
                float sle = ssum - sgt;
                bool flipGt = (sgt <= sle);
                float ssin = 0.0f, scos = 0.0f;
                for (int k = 0; k < m; ++k) {
                    float sc = ms[k];
                    float dj = ds[k];
                    float d = fabsf(dj - refdir);
                    if (d > PI_F) d = TWO_PI_F - d;
                    bool gt = d > HALF_PI_F;
                    bool flip = flipGt ? gt : !gt;
                    float adj_d = limit_period_f(dj + (flip ? PI_F : 0.0f));
                    float wgt = sc / denom;
                    ssin += sinf(adj_d) * wgt;
                    scos += cosf(adj_d) * wgt;
                }
                float theta = atan2f(ssin, scos);
                // s_fused: sort member scores descending, sum s_k^(k+1)
                for (int k = 1; k < m; ++k) {
                    float key = ms[k]; int p = k - 1;
                    while (p >= 0 && ms[p] < key) { ms[p+1] = ms[p]; --p; }
                    ms[p+1] = key;
                }
                float sf = 0.0f;
                for (int k = 0; k < m; ++k) sf += powf(ms[k], (float)(k+1));
                sf = fminf(sf, 1.0f);
                // corners range check
                float c_ = cosf(theta), s_ = sinf(theta);
                float wdim = cd4, ldim = cd5;
                const float xs[4]  = {0.5f, 0.5f, -0.5f, -0.5f};
                const float ys_[4] = {-0.5f, 0.5f, 0.5f, -0.5f};
                bool inr = true;
                for (int c = 0; c < 4; ++c) {
                    float cx = ldim * xs[c], cy = wdim * ys_[c];
                    float rx = cx*c_ - cy*s_ + cd0;
                    float ry = cx*s_ + cy*c_ + cd1;
                    inr = inr && (rx > -140.8f) && (rx < 140.8f) && (ry > -40.0f) && (ry < 40.0f);
                }
                fused[i*7+0]=cd0; fused[i*7+1]=cd1; fused[i*7+2]=cd2;
                fused[i*7+3]=cd3; fused[i*7+4]=cd4; fused[i*7+5]=cd5;
                fused[i*7+6]=theta;
                sfused[i] = sf;
                validArr[i] = inr ? 1 : 0;
            }
        }
        __syncthreads();
    }
}

// ---------------- Kernel 4: cumsum + gated output writes ----------------
__global__ void finalize_kernel(const float* __restrict__ fused,
                                const float* __restrict__ sfused,
                                const int* __restrict__ validArr,
                                const int* __restrict__ indices,
                                float* __restrict__ out, int n) {
    __shared__ int newidS[4096];
    __shared__ unsigned char validS[4096];
    __shared__ int scanBuf[1024];
    int tid = threadIdx.x;  // 1024
    int per = (n + 1023) >> 10;  // 4
    int base = tid * per;
    int v[8];
    int sum = 0;
    for (int k = 0; k < per && k < 8; ++k) {
        int j = base + k;
        int vv = (j < n) ? validArr[j] : 0;
        v[k] = vv; sum += vv;
    }
    scanBuf[tid] = sum;
    __syncthreads();
    for (int o = 1; o < 1024; o <<= 1) {
        int val = scanBuf[tid];
        int add = (tid >= o) ? scanBuf[tid - o] : 0;
        __syncthreads();
        scanBuf[tid] = val + add;
        __syncthreads();
    }
    int run = scanBuf[tid] - sum;
    for (int k = 0; k < per && k < 8; ++k) {
        int j = base + k;
        if (j < n) { run += v[k]; newidS[j] = run; validS[j] = (unsigned char)v[k]; }
    }
    __syncthreads();
    float* boxesO  = out;
    float* scoresO = out + (size_t)7*n;
    float* validO  = out + (size_t)8*n;
    float* idxO    = out + (size_t)9*n;
    for (int j = tid; j < n; j += 1024) {
        int vv = validS[j];
        #pragma unroll
        for (int k = 0; k < 7; ++k)
            boxesO[j*7+k] = vv ? fused[j*7+k] : 0.0f;
        scoresO[j] = vv ? sfused[j] : 0.0f;
        validO[j]  = vv ? 1.0f : 0.0f;
        int ind = indices[j];
        int safe = ind - 1; if (safe < 0) safe = 0;
        bool nv = (ind > 0) && (validS[safe] != 0);
        idxO[j] = nv ? (float)newidS[safe] : 0.0f;
    }
}

extern "C" void kernel_launch(void* const* d_in, const int* in_sizes, int n_in,
                              void* d_out, int out_size, void* d_ws, size_t ws_size,
                              hipStream_t stream) {
    const float* boxes  = (const float*)d_in[0];
    const float* scores = (const float*)d_in[1];
    int n = in_sizes[0] / 7;           // 4096
    int words = (n + 63) >> 6;         // 64

    char* ws = (char*)d_ws;
    size_t off = 0;
    u64* adjC = (u64*)(ws + off);
    off += (size_t)n * words * sizeof(u64);
    u64* S = (u64*)(ws + off); off += 64 * sizeof(u64);
    u64* R = (u64*)(ws + off); off += 64 * sizeof(u64);
    int* seedList = (int*)(ws + off); off += (size_t)n * sizeof(int);
    int* indices  = (int*)(ws + off); off += (size_t)n * sizeof(int);
    float* fused  = (float*)(ws + off); off += (size_t)n * 7 * sizeof(float);
    float* sfused = (float*)(ws + off); off += (size_t)n * sizeof(float);
    int* validArr = (int*)(ws + off); off += (size_t)n * sizeof(int);
    int* nclust   = (int*)(ws + off); off += sizeof(int);
    off = (off + 7) & ~(size_t)7;
    // zeroed region: occMask[64] + unresolvedCnt[ROUNDS_MAX] + barrier{cnt,gen}
    u64* occMask  = (u64*)(ws + off);
    int* unresolvedCnt = (int*)(ws + off + 64 * sizeof(u64));
    int* barrier  = (int*)(ws + off + 64 * sizeof(u64) + ROUNDS_MAX * sizeof(int));
    size_t zbytes = 64 * sizeof(u64) + ROUNDS_MAX * sizeof(int) + 2 * sizeof(int);

    hipMemsetAsync(occMask, 0, zbytes, stream);
    dim3 adjGrid(words, (n + 255) / 256);
    adj_kernel<<<adjGrid, 256, 0, stream>>>(boxes, adjC, occMask, n, words);
    mis_kernel<<<words, 256, 0, stream>>>(adjC, occMask, S, R, indices, seedList, nclust,
                                          unresolvedCnt, barrier, barrier + 1, n, words);
    fusion_kernel<<<512, 64, 0, stream>>>(boxes, scores, indices, seedList, nclust,
                                          adjC, fused, sfused, validArr, n, words);
    finalize_kernel<<<1, 1024, 0, stream>>>(fused, sfused, validArr, indices,
                                            (float*)d_out, n);
}